// Round 7
// baseline (2382.065 us; speedup 1.0000x reference)
//
#include <hip/hip_runtime.h>
#include <hip/hip_bf16.h>

typedef unsigned short u16;
typedef __bf16 bf16x8 __attribute__((ext_vector_type(8)));
typedef float f32x4 __attribute__((ext_vector_type(4)));

// Problem constants (B=4, S=2048, D=4096, E=8, r=8)
constexpr int Mdim = 8192;   // B*S
constexpr int Ndim = 4096;   // D (output features)
constexpr int Kdim = 4096;   // D (input features)
constexpr int ER   = 64;     // E*r
constexpr float LSCALE = 2.0f;  // alpha/r = 16/8

// round-to-nearest-even fp32 -> bf16 (finite inputs)
__device__ __forceinline__ u16 f2bf(float f) {
    union { float f; unsigned u; } v; v.f = f;
    unsigned r = v.u + 0x7fffu + ((v.u >> 16) & 1u);
    return (u16)(r >> 16);
}

#define GLOAD_LDS16(g, l)                                             \
    __builtin_amdgcn_global_load_lds(                                 \
        (const __attribute__((address_space(1))) void*)(g),           \
        (__attribute__((address_space(3))) void*)(l), 16, 0, 0)

// ---------------------------------------------------------------------------
// Kernel 1: W_eff[o,i] = W[o,i] + SCALE * sum_{er} Bcat[o,er]*Acat[er,i] (bf16)
// ---------------------------------------------------------------------------
__global__ __launch_bounds__(256) void weff_kernel(
    const float* __restrict__ W, const float* __restrict__ A,
    const float* __restrict__ Bm, u16* __restrict__ Wb)
{
    __shared__ __align__(16) float sAc[ER][128];
    __shared__ __align__(16) float sBc[64][ER];

    const int t  = threadIdx.x;
    const int i0 = blockIdx.x * 128;
    const int o0 = blockIdx.y * 64;

#pragma unroll
    for (int p = 0; p < 8; ++p) {
        int lin = p * 1024 + t * 4;
        int er = lin >> 7, ci = lin & 127;
        *(float4*)&sAc[er][ci] = *(const float4*)(A + (size_t)er * Kdim + i0 + ci);
    }
    {
        int ol = t >> 2;
        int c  = (t & 3) * 16;
#pragma unroll
        for (int q = 0; q < 2; ++q) {
            int er = c + q * 8;
            int e  = er >> 3;
            const float* src = Bm + ((size_t)e * Ndim + (o0 + ol)) * 8;
            *(float4*)&sBc[ol][er]     = *(const float4*)(src);
            *(float4*)&sBc[ol][er + 4] = *(const float4*)(src + 4);
        }
    }
    __syncthreads();

    const int tx = t & 31;
    const int ty = t >> 5;
    float acc[8][4] = {};
#pragma unroll 4
    for (int er = 0; er < ER; ++er) {
        float4 a = *(const float4*)&sAc[er][tx * 4];
#pragma unroll
        for (int q = 0; q < 8; ++q) {
            float bv = sBc[q * 8 + ty][er];
            acc[q][0] += bv * a.x;
            acc[q][1] += bv * a.y;
            acc[q][2] += bv * a.z;
            acc[q][3] += bv * a.w;
        }
    }
#pragma unroll
    for (int q = 0; q < 8; ++q) {
        int o = o0 + q * 8 + ty;
        const float4 w = *(const float4*)(W + (size_t)o * Kdim + i0 + tx * 4);
        ushort4 st;
        st.x = f2bf(w.x + LSCALE * acc[q][0]);
        st.y = f2bf(w.y + LSCALE * acc[q][1]);
        st.z = f2bf(w.z + LSCALE * acc[q][2]);
        st.w = f2bf(w.w + LSCALE * acc[q][3]);
        *(ushort4*)(Wb + (size_t)o * Kdim + i0 + tx * 4) = st;
    }
}

// ---------------------------------------------------------------------------
// Kernel 2: x fp32 -> bf16, 8 elements/thread
// ---------------------------------------------------------------------------
__global__ __launch_bounds__(256) void cvt_x_kernel(
    const float* __restrict__ x, u16* __restrict__ xb)
{
    size_t i = (size_t)blockIdx.x * blockDim.x + threadIdx.x;
    const float4 v0 = *(const float4*)(x + i * 8);
    const float4 v1 = *(const float4*)(x + i * 8 + 4);
    uint4 o;
    o.x = (unsigned)f2bf(v0.x) | ((unsigned)f2bf(v0.y) << 16);
    o.y = (unsigned)f2bf(v0.z) | ((unsigned)f2bf(v0.w) << 16);
    o.z = (unsigned)f2bf(v1.x) | ((unsigned)f2bf(v1.y) << 16);
    o.w = (unsigned)f2bf(v1.z) | ((unsigned)f2bf(v1.w) << 16);
    *(uint4*)(xb + i * 8) = o;
}

// ---------------------------------------------------------------------------
// Kernel 3: 256x256x32 GEMM, TWO blocks per CU (64 KiB LDS), one barrier per
// K-tile, wave-drift overlap. Rationale (round-7): with 128 KiB LDS only one
// block/CU was resident, so every tile-top barrier re-synced the whole CU and
// MFMA/LDS pipes serialized at the seam (MfmaUtil 54%). BK=32 halves LDS to
// 64 KiB -> 2 independent barrier domains per CU; block A's DS burst overlaps
// block B's MFMA clusters. Read traffic per K unchanged (12 b128/wave/tile).
// Held-back m-half: mh1's 16 MFMA of tile T run at tile T+1's top, covering
// the post-barrier DS burst (WAR resolved by program order).
// 512 threads = 8 waves (2 M x 4 N); per-wave 128x64 out = acc[8][4] f32x4.
// LDS 64 KiB: per buf {A[256][32], B[256][32]} bf16, double-buffered.
// Swizzle: LDS[row][cl] = G[row][cl ^ ((row>>1)&3)] (16B chunks, involution;
// pre-swizzled global source, same XOR on ds_read; <=2 lanes/bank).
// Tile-top lgkmcnt(0) is REQUIRED: afB's ds_reads are only consumed after
// the next barrier, so the drain protects the buffer being overwritten.
// ---------------------------------------------------------------------------
constexpr int BM = 256, BN = 256, BK = 32;
constexpr int NT = Kdim / BK;  // 128

__global__ __launch_bounds__(512, 4) void gemm_bias_kernel(
    const u16* __restrict__ Xb, const u16* __restrict__ Wb,
    const float* __restrict__ bias, float* __restrict__ C)
{
    __shared__ __align__(16) u16 lds[32768];   // 64 KiB

    const int t    = threadIdx.x;
    const int lane = t & 63;
    const int wv   = t >> 6;
    const int wr   = wv >> 2;   // 0..1
    const int wc   = wv & 3;    // 0..3

    // XCD-aware swizzle: 512 blocks = 8 XCDs x 64; each XCD owns a 16x4 region
    const int wg  = blockIdx.x;
    const int xcd = wg & 7, lid = wg >> 3;
    const int mt  = (xcd & 1) * 16 + (lid >> 2);   // 0..31
    const int ntl = (xcd >> 1) * 4 + (lid & 3);    // 0..15
    const int bm  = mt * BM;
    const int bn  = ntl * BN;

    u16* b0 = lds;            // buf: A at [0,8192), B at [8192,16384)
    u16* b1 = lds + 16384;

    // --- staging: 4 x global_load_lds(16B) per thread per K-tile ---
    // chunk c (0..1023): row = c>>2, col-chunk cl = c&3. LDS dest linear;
    // global source chunk = cl ^ ((row>>1)&3) = (c ^ (c>>3)) & 3.
    const u16* gSrc[4]; int dOff[4];
#pragma unroll
    for (int i = 0; i < 4; ++i) {
        const int sub = i & 1;
        const int isB = i >> 1;
        const int c   = sub * 512 + t;                    // 0..1023
        const int row = c >> 2;                           // 0..255
        const int scl = ((c ^ (c >> 3)) & 3) * 8;         // swizzled col (u16)
        gSrc[i] = (isB ? Wb + (size_t)(bn + row) * Kdim
                       : Xb + (size_t)(bm + row) * Kdim) + scl;
        dOff[i] = isB * 8192 + c * 8;
    }

    // --- fragment ds_read addressing (swizzled) ---
    // lane l reads row (base16 + fr), k-chunk (l>>4); stored chunk =
    // (l>>4) ^ ((row>>1)&3); base16 multiple of 16 -> key = (fr>>1)&3.
    const int fr = lane & 15;
    const int cp = (((lane >> 4) ^ (fr >> 1)) & 3) * 8;

    f32x4 acc[8][4];
#pragma unroll
    for (int i = 0; i < 8; ++i)
#pragma unroll
        for (int j = 0; j < 4; ++j)
            acc[i][j] = f32x4{0.f, 0.f, 0.f, 0.f};

    bf16x8 afA[4], afB[4];   // A m-half fragments (mh0 / mh1)
    bf16x8 bfr[4];           // all four B n-fragments

#define DS_AFRAG(BUF, ARR, MH)                                                \
    _Pragma("unroll")                                                         \
    for (int mi = 0; mi < 4; ++mi)                                            \
        ARR[mi] = *(const bf16x8*)                                            \
            &(BUF)[(wr * 128 + (MH) * 64 + mi * 16 + fr) * 32 + cp];

#define DS_BFRAG(BUF)                                                         \
    _Pragma("unroll")                                                         \
    for (int ni = 0; ni < 4; ++ni)                                            \
        bfr[ni] = *(const bf16x8*)                                            \
            &(BUF)[8192 + (wc * 64 + ni * 16 + fr) * 32 + cp];

#define MQH(ARR, MH)                                                          \
    __builtin_amdgcn_s_setprio(1);                                            \
    _Pragma("unroll")                                                         \
    for (int mi = 0; mi < 4; ++mi)                                            \
        _Pragma("unroll")                                                     \
        for (int ni = 0; ni < 4; ++ni)                                        \
            acc[(MH)*4 + mi][ni] = __builtin_amdgcn_mfma_f32_16x16x32_bf16(   \
                ARR[mi], bfr[ni], acc[(MH)*4 + mi][ni], 0, 0, 0);             \
    __builtin_amdgcn_s_setprio(0);

#define FENCE asm volatile("" ::: "memory")
#define BAR   __builtin_amdgcn_s_barrier(); FENCE

    // TILE(T): one barrier. vmcnt(0): tile T's 4 gloads (issued in T-1)
    // landed; lgkmcnt(0): this wave's afB reads (consumed only after the
    // barrier by the held MQH) are complete -> safe for others to overwrite.
    // Body: held MQH(afB,1) of T-1 [before DS_BFRAG overwrites bfr], issue
    // gloads(T+1) into NXT, 12 ds_reads of CUR, MQH(afA,0); afB held to T+1.
#define TILE(CUR, NXT, FIRST, LAST)                                           \
    {                                                                         \
        asm volatile("s_waitcnt vmcnt(0) lgkmcnt(0)" ::: "memory");           \
        BAR;                                                                  \
        if (!(FIRST)) { MQH(afB, 1); }                                        \
        if (!(LAST)) {                                                        \
            _Pragma("unroll")                                                 \
            for (int i = 0; i < 4; ++i)                                       \
                GLOAD_LDS16(gSrc[i] + koff, (NXT) + dOff[i]);                 \
            koff += 32;                                                       \
        }                                                                     \
        DS_AFRAG(CUR, afA, 0);                                                \
        DS_BFRAG(CUR);                                                        \
        MQH(afA, 0);                                                          \
        DS_AFRAG(CUR, afB, 1);                                                \
    }

    // prologue: issue tile 0 into buf0
#pragma unroll
    for (int i = 0; i < 4; ++i) GLOAD_LDS16(gSrc[i], b0 + dOff[i]);

    int koff = 32;   // k element-offset of the next tile to issue (tile 1)

    TILE(b0, b1, 1, 0);                 // T0
#pragma unroll 1
    for (int t2 = 0; t2 < (NT - 2) / 2; ++t2) {   // T1..T126 (63 pairs)
        TILE(b1, b0, 0, 0);
        TILE(b0, b1, 0, 0);
    }
    TILE(b1, b0, 0, 1);                 // T127 (no prefetch)
    MQH(afB, 1);                        // drain held mh1 of T127

#undef TILE
#undef MQH
#undef DS_BFRAG
#undef DS_AFRAG

    // epilogue: bias add + store (C/D layout: col=lane&15, row=(lane>>4)*4+j)
#pragma unroll
    for (int ni = 0; ni < 4; ++ni) {
        const int col = bn + wc * 64 + ni * 16 + (lane & 15);
        const float bv = bias[col];
#pragma unroll
        for (int mi = 0; mi < 8; ++mi) {
            const int rbase = bm + wr * 128 + mi * 16 + (lane >> 4) * 4;
#pragma unroll
            for (int j = 0; j < 4; ++j)
                C[(size_t)(rbase + j) * Ndim + col] = acc[mi][ni][j] + bv;
        }
    }
}

// ---------------------------------------------------------------------------
// Fallback (only if ws too small): slow but correct fp32 row-per-block kernel
// ---------------------------------------------------------------------------
__global__ __launch_bounds__(256) void naive_row_kernel(
    const float* __restrict__ x, const float* __restrict__ W,
    const float* __restrict__ bias, const float* __restrict__ A,
    const float* __restrict__ Bm, float* __restrict__ out)
{
    __shared__ float sx[Kdim];
    __shared__ float st[ER];
    const int m = blockIdx.x;
    const float* xr = x + (size_t)m * Kdim;
    for (int i = threadIdx.x; i < Kdim; i += 256) sx[i] = xr[i];
    __syncthreads();
    if (threadIdx.x < ER) {
        const float* ar = A + (size_t)threadIdx.x * Kdim;
        float s = 0.f;
        for (int i = 0; i < Kdim; ++i) s += sx[i] * ar[i];
        st[threadIdx.x] = s;
    }
    __syncthreads();
    for (int o = threadIdx.x; o < Ndim; o += 256) {
        const float* wr = W + (size_t)o * Kdim;
        float s = bias[o];
        for (int i = 0; i < Kdim; ++i) s += sx[i] * wr[i];
        float l = 0.f;
        for (int e = 0; e < 8; ++e) {
            const float* bp = Bm + ((size_t)e * Ndim + o) * 8;
            for (int r = 0; r < 8; ++r) l += st[e * 8 + r] * bp[r];
        }
        out[(size_t)m * Ndim + o] = s + LSCALE * l;
    }
}

extern "C" void kernel_launch(void* const* d_in, const int* in_sizes, int n_in,
                              void* d_out, int out_size, void* d_ws, size_t ws_size,
                              hipStream_t stream)
{
    const float* x  = (const float*)d_in[0];
    const float* W  = (const float*)d_in[1];
    const float* b  = (const float*)d_in[2];
    const float* A  = (const float*)d_in[3];
    const float* Bm = (const float*)d_in[4];
    float* out = (float*)d_out;

    const size_t xb_bytes = (size_t)Mdim * Kdim * 2;   // 64 MB
    const size_t wb_bytes = (size_t)Ndim * Kdim * 2;   // 32 MB

    if (ws_size >= xb_bytes + wb_bytes) {
        u16* Xb = (u16*)d_ws;
        u16* Wb = (u16*)((char*)d_ws + xb_bytes);
        cvt_x_kernel<<<(Mdim * (size_t)Kdim) / 8 / 256, 256, 0, stream>>>(x, Xb);
        weff_kernel<<<dim3(Kdim / 128, Ndim / 64), 256, 0, stream>>>(W, A, Bm, Wb);
        gemm_bias_kernel<<<dim3((Mdim / BM) * (Ndim / BN)), 512, 0, stream>>>(Xb, Wb, b, out);
    } else {
        naive_row_kernel<<<Mdim, 256, 0, stream>>>(x, W, b, A, Bm, out);
    }
}

// Round 8
// 327.044 us; speedup vs baseline: 7.2836x; 7.2836x over previous
//
#include <hip/hip_runtime.h>
#include <hip/hip_bf16.h>

typedef unsigned short u16;
typedef __bf16 bf16x8 __attribute__((ext_vector_type(8)));
typedef float f32x4 __attribute__((ext_vector_type(4)));

// Problem constants (B=4, S=2048, D=4096, E=8, r=8)
constexpr int Mdim = 8192;   // B*S
constexpr int Ndim = 4096;   // D (output features)
constexpr int Kdim = 4096;   // D (input features)
constexpr int ER   = 64;     // E*r
constexpr float LSCALE = 2.0f;  // alpha/r = 16/8

// round-to-nearest-even fp32 -> bf16 (finite inputs)
__device__ __forceinline__ u16 f2bf(float f) {
    union { float f; unsigned u; } v; v.f = f;
    unsigned r = v.u + 0x7fffu + ((v.u >> 16) & 1u);
    return (u16)(r >> 16);
}

#define GLOAD_LDS16(g, l)                                             \
    __builtin_amdgcn_global_load_lds(                                 \
        (const __attribute__((address_space(1))) void*)(g),           \
        (__attribute__((address_space(3))) void*)(l), 16, 0, 0)

// ---------------------------------------------------------------------------
// Kernel 1: W_eff[o,i] = W[o,i] + SCALE * sum_{er} Bcat[o,er]*Acat[er,i] (bf16)
// ---------------------------------------------------------------------------
__global__ __launch_bounds__(256) void weff_kernel(
    const float* __restrict__ W, const float* __restrict__ A,
    const float* __restrict__ Bm, u16* __restrict__ Wb)
{
    __shared__ __align__(16) float sAc[ER][128];
    __shared__ __align__(16) float sBc[64][ER];

    const int t  = threadIdx.x;
    const int i0 = blockIdx.x * 128;
    const int o0 = blockIdx.y * 64;

#pragma unroll
    for (int p = 0; p < 8; ++p) {
        int lin = p * 1024 + t * 4;
        int er = lin >> 7, ci = lin & 127;
        *(float4*)&sAc[er][ci] = *(const float4*)(A + (size_t)er * Kdim + i0 + ci);
    }
    {
        int ol = t >> 2;
        int c  = (t & 3) * 16;
#pragma unroll
        for (int q = 0; q < 2; ++q) {
            int er = c + q * 8;
            int e  = er >> 3;
            const float* src = Bm + ((size_t)e * Ndim + (o0 + ol)) * 8;
            *(float4*)&sBc[ol][er]     = *(const float4*)(src);
            *(float4*)&sBc[ol][er + 4] = *(const float4*)(src + 4);
        }
    }
    __syncthreads();

    const int tx = t & 31;
    const int ty = t >> 5;
    float acc[8][4] = {};
#pragma unroll 4
    for (int er = 0; er < ER; ++er) {
        float4 a = *(const float4*)&sAc[er][tx * 4];
#pragma unroll
        for (int q = 0; q < 8; ++q) {
            float bv = sBc[q * 8 + ty][er];
            acc[q][0] += bv * a.x;
            acc[q][1] += bv * a.y;
            acc[q][2] += bv * a.z;
            acc[q][3] += bv * a.w;
        }
    }
#pragma unroll
    for (int q = 0; q < 8; ++q) {
        int o = o0 + q * 8 + ty;
        const float4 w = *(const float4*)(W + (size_t)o * Kdim + i0 + tx * 4);
        ushort4 st;
        st.x = f2bf(w.x + LSCALE * acc[q][0]);
        st.y = f2bf(w.y + LSCALE * acc[q][1]);
        st.z = f2bf(w.z + LSCALE * acc[q][2]);
        st.w = f2bf(w.w + LSCALE * acc[q][3]);
        *(ushort4*)(Wb + (size_t)o * Kdim + i0 + tx * 4) = st;
    }
}

// ---------------------------------------------------------------------------
// Kernel 2: x fp32 -> bf16, 8 elements/thread
// ---------------------------------------------------------------------------
__global__ __launch_bounds__(256) void cvt_x_kernel(
    const float* __restrict__ x, u16* __restrict__ xb)
{
    size_t i = (size_t)blockIdx.x * blockDim.x + threadIdx.x;
    const float4 v0 = *(const float4*)(x + i * 8);
    const float4 v1 = *(const float4*)(x + i * 8 + 4);
    uint4 o;
    o.x = (unsigned)f2bf(v0.x) | ((unsigned)f2bf(v0.y) << 16);
    o.y = (unsigned)f2bf(v0.z) | ((unsigned)f2bf(v0.w) << 16);
    o.z = (unsigned)f2bf(v1.x) | ((unsigned)f2bf(v1.y) << 16);
    o.w = (unsigned)f2bf(v1.z) | ((unsigned)f2bf(v1.w) << 16);
    *(uint4*)(xb + i * 8) = o;
}

// ---------------------------------------------------------------------------
// Kernel 3: 128x256x32 GEMM, 4-wave blocks, TWO blocks per CU.
// Round-8 rationale: round-7's __launch_bounds__(512,4) capped regs at 128
// and spilled acc (VGPR=64, 11.7GB scratch traffic). This keeps the proven
// 256-reg/wave budget (round 6: 128 VGPR + 128 AGPR) but shrinks the BLOCK:
// 256 threads = 4 waves (1 wave/SIMD), LDS 48 KiB -> 2 blocks/CU resident
// (regs: 2 waves/SIMD x 256 = 512-reg file, LDS: 2x48 <= 160 KiB). The two
// blocks have independent barrier domains: one block's tile-top DS burst
// overlaps the other's MFMA clusters -- the decorrelation round 6 lacked.
// Per-wave rhythm identical to round 6: out 128x64 (acc[8][4]), 12
// ds_read_b128 + 32 MFMA per K-tile, held m-half (afB) crosses the barrier.
// LDS per buf: A[128][32] (8KB) + B[256][32] (16KB); double-buffered.
// Swizzle (both-sides, involution): stored chunk = global chunk ^ ((row>>1)&3)
// via pre-swizzled source; ds_read applies the same XOR; <=2 lanes/bank.
// Tile-top lgkmcnt(0) REQUIRED (protects held afB's source buffer).
// ---------------------------------------------------------------------------
constexpr int BM = 128, BN = 256, BK = 32;
constexpr int NT = Kdim / BK;  // 128

__global__ __launch_bounds__(256, 2) void gemm_bias_kernel(
    const u16* __restrict__ Xb, const u16* __restrict__ Wb,
    const float* __restrict__ bias, float* __restrict__ C)
{
    __shared__ __align__(16) u16 lds[24576];   // 48 KiB

    const int t    = threadIdx.x;
    const int lane = t & 63;
    const int wv   = t >> 6;    // 0..3 = n-position of this wave

    // XCD-aware swizzle: 1024 blocks = 8 XCDs x 128; per XCD a 32m x 4n region
    const int wg  = blockIdx.x;
    const int xcd = wg & 7, lid = wg >> 3;
    const int mt  = (xcd & 1) * 32 + (lid >> 2);   // 0..63
    const int ntl = (xcd >> 1) * 4 + (lid & 3);    // 0..15
    const int bm  = mt * BM;
    const int bn  = ntl * BN;

    u16* b0 = lds;            // buf: A at [0,4096), B at [4096,12288) u16
    u16* b1 = lds + 12288;

    // --- staging: 6 x global_load_lds(16B) per thread per K-tile ---
    // A: chunks 0..511 (2/thread); B: chunks 0..1023 (4/thread).
    // chunk c: row = c>>2, col-chunk = c&3; LDS dest linear; global source
    // chunk = (c ^ (c>>3)) & 3  (i.e. col ^ ((row>>1)&3), involution).
    const u16* gSrc[6]; int dOff[6];
#pragma unroll
    for (int i = 0; i < 6; ++i) {
        const int isB = (i >= 2) ? 1 : 0;
        const int c   = (isB ? (i - 2) : i) * 256 + t;    // A:0..511 B:0..1023
        const int row = c >> 2;
        const int scl = ((c ^ (c >> 3)) & 3) * 8;         // swizzled col (u16)
        gSrc[i] = (isB ? Wb + (size_t)(bn + row) * Kdim
                       : Xb + (size_t)(bm + row) * Kdim) + scl;
        dOff[i] = isB * 4096 + c * 8;
    }

    // --- fragment ds_read addressing (swizzled) ---
    const int fr = lane & 15;
    const int cp = (((lane >> 4) ^ (fr >> 1)) & 3) * 8;

    f32x4 acc[8][4];
#pragma unroll
    for (int i = 0; i < 8; ++i)
#pragma unroll
        for (int j = 0; j < 4; ++j)
            acc[i][j] = f32x4{0.f, 0.f, 0.f, 0.f};

    bf16x8 afA[4], afB[4];   // A m-half fragments (rows 0..63 / 64..127)
    bf16x8 bfr[4];           // four B n-fragments (this wave's 64 cols)

#define DS_AFRAG(BUF, ARR, MH)                                                \
    _Pragma("unroll")                                                         \
    for (int mi = 0; mi < 4; ++mi)                                            \
        ARR[mi] = *(const bf16x8*)                                            \
            &(BUF)[((MH) * 64 + mi * 16 + fr) * 32 + cp];

#define DS_BFRAG(BUF)                                                         \
    _Pragma("unroll")                                                         \
    for (int ni = 0; ni < 4; ++ni)                                            \
        bfr[ni] = *(const bf16x8*)                                            \
            &(BUF)[4096 + (wv * 64 + ni * 16 + fr) * 32 + cp];

#define MQH(ARR, MH)                                                          \
    __builtin_amdgcn_s_setprio(1);                                            \
    _Pragma("unroll")                                                         \
    for (int mi = 0; mi < 4; ++mi)                                            \
        _Pragma("unroll")                                                     \
        for (int ni = 0; ni < 4; ++ni)                                        \
            acc[(MH)*4 + mi][ni] = __builtin_amdgcn_mfma_f32_16x16x32_bf16(   \
                ARR[mi], bfr[ni], acc[(MH)*4 + mi][ni], 0, 0, 0);             \
    __builtin_amdgcn_s_setprio(0);

#define FENCE asm volatile("" ::: "memory")
#define BAR   __builtin_amdgcn_s_barrier(); FENCE

    // TILE(T): one barrier per K-tile (round-6 schedule). vmcnt(0): tile T's
    // 6 gloads (issued in T-1) landed; lgkmcnt(0): this wave's afB reads are
    // complete -> safe for the next stage to overwrite that buffer.
    // Body: held MQH(afB,1) of T-1 [before DS_BFRAG overwrites bfr], issue
    // gloads(T+1) into NXT, 12 ds_reads of CUR, MQH(afA,0); afB held to T+1.
#define TILE(CUR, NXT, FIRST, LAST)                                           \
    {                                                                         \
        asm volatile("s_waitcnt vmcnt(0) lgkmcnt(0)" ::: "memory");           \
        BAR;                                                                  \
        if (!(FIRST)) { MQH(afB, 1); }                                        \
        if (!(LAST)) {                                                        \
            _Pragma("unroll")                                                 \
            for (int i = 0; i < 6; ++i)                                       \
                GLOAD_LDS16(gSrc[i] + koff, (NXT) + dOff[i]);                 \
            koff += 32;                                                       \
        }                                                                     \
        DS_AFRAG(CUR, afA, 0);                                                \
        DS_BFRAG(CUR);                                                        \
        MQH(afA, 0);                                                          \
        DS_AFRAG(CUR, afB, 1);                                                \
    }

    // prologue: issue tile 0 into buf0
#pragma unroll
    for (int i = 0; i < 6; ++i) GLOAD_LDS16(gSrc[i], b0 + dOff[i]);

    int koff = 32;   // k element-offset of the next tile to issue (tile 1)

    TILE(b0, b1, 1, 0);                 // T0
#pragma unroll 1
    for (int t2 = 0; t2 < (NT - 2) / 2; ++t2) {   // T1..T126 (63 pairs)
        TILE(b1, b0, 0, 0);
        TILE(b0, b1, 0, 0);
    }
    TILE(b1, b0, 0, 1);                 // T127 (no prefetch)
    MQH(afB, 1);                        // drain held mh1 of T127

#undef TILE
#undef MQH
#undef DS_BFRAG
#undef DS_AFRAG

    // epilogue: bias add + store (C/D layout: col=lane&15, row=(lane>>4)*4+j)
#pragma unroll
    for (int ni = 0; ni < 4; ++ni) {
        const int col = bn + wv * 64 + ni * 16 + (lane & 15);
        const float bv = bias[col];
#pragma unroll
        for (int mi = 0; mi < 8; ++mi) {
            const int rbase = bm + mi * 16 + (lane >> 4) * 4;
#pragma unroll
            for (int j = 0; j < 4; ++j)
                C[(size_t)(rbase + j) * Ndim + col] = acc[mi][ni][j] + bv;
        }
    }
}

// ---------------------------------------------------------------------------
// Fallback (only if ws too small): slow but correct fp32 row-per-block kernel
// ---------------------------------------------------------------------------
__global__ __launch_bounds__(256) void naive_row_kernel(
    const float* __restrict__ x, const float* __restrict__ W,
    const float* __restrict__ bias, const float* __restrict__ A,
    const float* __restrict__ Bm, float* __restrict__ out)
{
    __shared__ float sx[Kdim];
    __shared__ float st[ER];
    const int m = blockIdx.x;
    const float* xr = x + (size_t)m * Kdim;
    for (int i = threadIdx.x; i < Kdim; i += 256) sx[i] = xr[i];
    __syncthreads();
    if (threadIdx.x < ER) {
        const float* ar = A + (size_t)threadIdx.x * Kdim;
        float s = 0.f;
        for (int i = 0; i < Kdim; ++i) s += sx[i] * ar[i];
        st[threadIdx.x] = s;
    }
    __syncthreads();
    for (int o = threadIdx.x; o < Ndim; o += 256) {
        const float* wr = W + (size_t)o * Kdim;
        float s = bias[o];
        for (int i = 0; i < Kdim; ++i) s += sx[i] * wr[i];
        float l = 0.f;
        for (int e = 0; e < 8; ++e) {
            const float* bp = Bm + ((size_t)e * Ndim + o) * 8;
            for (int r = 0; r < 8; ++r) l += st[e * 8 + r] * bp[r];
        }
        out[(size_t)m * Ndim + o] = s + LSCALE * l;
    }
}

extern "C" void kernel_launch(void* const* d_in, const int* in_sizes, int n_in,
                              void* d_out, int out_size, void* d_ws, size_t ws_size,
                              hipStream_t stream)
{
    const float* x  = (const float*)d_in[0];
    const float* W  = (const float*)d_in[1];
    const float* b  = (const float*)d_in[2];
    const float* A  = (const float*)d_in[3];
    const float* Bm = (const float*)d_in[4];
    float* out = (float*)d_out;

    const size_t xb_bytes = (size_t)Mdim * Kdim * 2;   // 64 MB
    const size_t wb_bytes = (size_t)Ndim * Kdim * 2;   // 32 MB

    if (ws_size >= xb_bytes + wb_bytes) {
        u16* Xb = (u16*)d_ws;
        u16* Wb = (u16*)((char*)d_ws + xb_bytes);
        cvt_x_kernel<<<(Mdim * (size_t)Kdim) / 8 / 256, 256, 0, stream>>>(x, Xb);
        weff_kernel<<<dim3(Kdim / 128, Ndim / 64), 256, 0, stream>>>(W, A, Bm, Wb);
        gemm_bias_kernel<<<dim3((Mdim / BM) * (Ndim / BN)), 256, 0, stream>>>(Xb, Wb, b, out);
    } else {
        naive_row_kernel<<<Mdim, 256, 0, stream>>>(x, W, b, A, Bm, out);
    }
}

// Round 9
// 306.701 us; speedup vs baseline: 7.7667x; 1.0663x over previous
//
#include <hip/hip_runtime.h>
#include <hip/hip_bf16.h>

typedef unsigned short u16;
typedef __bf16 bf16x8 __attribute__((ext_vector_type(8)));
typedef float f32x16 __attribute__((ext_vector_type(16)));

// Problem constants (B=4, S=2048, D=4096, E=8, r=8)
constexpr int Mdim = 8192;   // B*S
constexpr int Ndim = 4096;   // D (output features)
constexpr int Kdim = 4096;   // D (input features)
constexpr int ER   = 64;     // E*r
constexpr float LSCALE = 2.0f;  // alpha/r = 16/8

// round-to-nearest-even fp32 -> bf16 (finite inputs)
__device__ __forceinline__ u16 f2bf(float f) {
    union { float f; unsigned u; } v; v.f = f;
    unsigned r = v.u + 0x7fffu + ((v.u >> 16) & 1u);
    return (u16)(r >> 16);
}

#define GLOAD_LDS16(g, l)                                             \
    __builtin_amdgcn_global_load_lds(                                 \
        (const __attribute__((address_space(1))) void*)(g),           \
        (__attribute__((address_space(3))) void*)(l), 16, 0, 0)

// ---------------------------------------------------------------------------
// Kernel 1: W_eff[o,i] = W[o,i] + SCALE * sum_{er} Bcat[o,er]*Acat[er,i] (bf16)
// ---------------------------------------------------------------------------
__global__ __launch_bounds__(256) void weff_kernel(
    const float* __restrict__ W, const float* __restrict__ A,
    const float* __restrict__ Bm, u16* __restrict__ Wb)
{
    __shared__ __align__(16) float sAc[ER][128];
    __shared__ __align__(16) float sBc[64][ER];

    const int t  = threadIdx.x;
    const int i0 = blockIdx.x * 128;
    const int o0 = blockIdx.y * 64;

#pragma unroll
    for (int p = 0; p < 8; ++p) {
        int lin = p * 1024 + t * 4;
        int er = lin >> 7, ci = lin & 127;
        *(float4*)&sAc[er][ci] = *(const float4*)(A + (size_t)er * Kdim + i0 + ci);
    }
    {
        int ol = t >> 2;
        int c  = (t & 3) * 16;
#pragma unroll
        for (int q = 0; q < 2; ++q) {
            int er = c + q * 8;
            int e  = er >> 3;
            const float* src = Bm + ((size_t)e * Ndim + (o0 + ol)) * 8;
            *(float4*)&sBc[ol][er]     = *(const float4*)(src);
            *(float4*)&sBc[ol][er + 4] = *(const float4*)(src + 4);
        }
    }
    __syncthreads();

    const int tx = t & 31;
    const int ty = t >> 5;
    float acc[8][4] = {};
#pragma unroll 4
    for (int er = 0; er < ER; ++er) {
        float4 a = *(const float4*)&sAc[er][tx * 4];
#pragma unroll
        for (int q = 0; q < 8; ++q) {
            float bv = sBc[q * 8 + ty][er];
            acc[q][0] += bv * a.x;
            acc[q][1] += bv * a.y;
            acc[q][2] += bv * a.z;
            acc[q][3] += bv * a.w;
        }
    }
#pragma unroll
    for (int q = 0; q < 8; ++q) {
        int o = o0 + q * 8 + ty;
        const float4 w = *(const float4*)(W + (size_t)o * Kdim + i0 + tx * 4);
        ushort4 st;
        st.x = f2bf(w.x + LSCALE * acc[q][0]);
        st.y = f2bf(w.y + LSCALE * acc[q][1]);
        st.z = f2bf(w.z + LSCALE * acc[q][2]);
        st.w = f2bf(w.w + LSCALE * acc[q][3]);
        *(ushort4*)(Wb + (size_t)o * Kdim + i0 + tx * 4) = st;
    }
}

// ---------------------------------------------------------------------------
// Kernel 2: x fp32 -> bf16, 8 elements/thread
// ---------------------------------------------------------------------------
__global__ __launch_bounds__(256) void cvt_x_kernel(
    const float* __restrict__ x, u16* __restrict__ xb)
{
    size_t i = (size_t)blockIdx.x * blockDim.x + threadIdx.x;
    const float4 v0 = *(const float4*)(x + i * 8);
    const float4 v1 = *(const float4*)(x + i * 8 + 4);
    uint4 o;
    o.x = (unsigned)f2bf(v0.x) | ((unsigned)f2bf(v0.y) << 16);
    o.y = (unsigned)f2bf(v0.z) | ((unsigned)f2bf(v0.w) << 16);
    o.z = (unsigned)f2bf(v1.x) | ((unsigned)f2bf(v1.y) << 16);
    o.w = (unsigned)f2bf(v1.z) | ((unsigned)f2bf(v1.w) << 16);
    *(uint4*)(xb + i * 8) = o;
}

// ---------------------------------------------------------------------------
// Kernel 3: 256x256x64 GEMM, FOUR waves of 128x128 output each, 32x32x16 MFMA.
// Round-9 rationale: r6's ceiling was the LDS-read pipe (8 waves x 24KB/tile
// = 192KB reads ~= MFMA floor -> serialization at ~4310 cyc/tile). 2x2 wave
// grid with 128x128/wave halves the sharing redundancy: 4 x 32KB = 128KB
// reads/tile (LDS floor ~2050 cyc) and 32x32x16 MFMA cuts the MFMA floor to
// 2066 cyc (8.07 vs 9.7 cyc per 32K FLOP). acc = 4x4 f32x16 = 256 regs ->
// 1 wave/SIMD (__launch_bounds__(256,1), 512-reg budget, no spill).
// Schedule: r6's proven one-barrier drift: per K-tile {vmcnt(0)+lgkmcnt(0)
// +barrier; held MFMA(ks3 of T-1); 16 gloads(T+1); ds/MFMA ping-pong over
// ks=0..2; ks3 read last and held}. LDS layout/staging/swizzle identical to
// r6 (BK=64, chunk ^= row&7 both-sides involution; conflict-free).
// C/D layout (32x32): col=lane&31, row=(reg&3)+8*(reg>>2)+4*(lane>>5).
// ---------------------------------------------------------------------------
constexpr int BM = 256, BN = 256, BK = 64;
constexpr int NT = Kdim / BK;  // 64

__global__ __launch_bounds__(256, 1) void gemm_bias_kernel(
    const u16* __restrict__ Xb, const u16* __restrict__ Wb,
    const float* __restrict__ bias, float* __restrict__ C)
{
    __shared__ __align__(16) u16 lds[65536];   // 128 KiB

    const int t    = threadIdx.x;
    const int lane = t & 63;
    const int wv   = t >> 6;    // 0..3
    const int wr2  = wv >> 1;   // m-half: rows wr2*128
    const int wc2  = wv & 1;    // n-half: cols wc2*128

    // XCD-aware swizzle: 512 blocks = 8 XCDs x 64; each XCD owns a 16x4 region
    const int wg  = blockIdx.x;
    const int xcd = wg & 7, lid = wg >> 3;
    const int mt  = (xcd & 1) * 16 + (lid >> 2);   // 0..31
    const int ntl = (xcd >> 1) * 4 + (lid & 3);    // 0..15
    const int bm  = mt * BM;
    const int bn  = ntl * BN;

    u16* b0 = lds;            // window: A at [0,16384), B at [16384,32768) u16
    u16* b1 = lds + 32768;

    // --- staging: 16 x global_load_lds(16B) per thread per K-tile ---
    // i<8: A chunk c=i*256+t ; i>=8: B chunk c=(i-8)*256+t (c in 0..2047).
    // LDS dest linear (c*16B); global source col chunk = (c ^ (c>>3)) & 7
    // (= col-chunk ^ (row&7), involution).
    const u16* gSrc[16]; int dOff[16];
#pragma unroll
    for (int i = 0; i < 16; ++i) {
        const int isB = i >> 3;
        const int c   = (i & 7) * 256 + t;                // 0..2047
        const int row = c >> 3;                           // 0..255
        const int scl = ((c ^ (c >> 3)) & 7) * 8;         // swizzled col (u16)
        gSrc[i] = (isB ? Wb + (size_t)(bn + row) * Kdim
                       : Xb + (size_t)(bm + row) * Kdim) + scl;
        dOff[i] = isB * 16384 + c * 8;
    }

    // --- fragment ds_read addressing (swizzled) ---
    // lane reads row R+l31 (R mult of 32), k-chunk kc = ks*2 + (lane>>5);
    // stored chunk = kc ^ (row&7), key = l31&7.
    const int l31   = lane & 31;
    const int khalf = lane >> 5;
    const int key   = l31 & 7;
    int cpk[4];
#pragma unroll
    for (int ks = 0; ks < 4; ++ks)
        cpk[ks] = (((ks * 2 + khalf) ^ key) & 7) * 8;

    f32x16 acc[4][4];
#pragma unroll
    for (int i = 0; i < 4; ++i)
#pragma unroll
        for (int j = 0; j < 4; ++j)
            acc[i][j] = (f32x16)(0.0f);

    bf16x8 aP[4], bP[4];   // ping fragment set (ks even)
    bf16x8 aQ[4], bQ[4];   // pong fragment set (ks odd; ks3 held across tiles)

#define DS_K(BUF, AR, BR, KS)                                                 \
    _Pragma("unroll")                                                         \
    for (int mi = 0; mi < 4; ++mi)                                            \
        AR[mi] = *(const bf16x8*)                                             \
            &(BUF)[(wr2 * 128 + mi * 32 + l31) * 64 + cpk[KS]];               \
    _Pragma("unroll")                                                         \
    for (int ni = 0; ni < 4; ++ni)                                            \
        BR[ni] = *(const bf16x8*)                                             \
            &(BUF)[16384 + (wc2 * 128 + ni * 32 + l31) * 64 + cpk[KS]];

#define MQ(AR, BR)                                                            \
    _Pragma("unroll")                                                         \
    for (int mi = 0; mi < 4; ++mi)                                            \
        _Pragma("unroll")                                                     \
        for (int ni = 0; ni < 4; ++ni)                                        \
            acc[mi][ni] = __builtin_amdgcn_mfma_f32_32x32x16_bf16(            \
                AR[mi], BR[ni], acc[mi][ni], 0, 0, 0);

#define FENCE asm volatile("" ::: "memory")
#define BAR   __builtin_amdgcn_s_barrier(); FENCE

    // TILE(T): one barrier per K-tile. At top: lgkmcnt(0) drains this wave's
    // ks3 reads of CUR (so post-barrier gloads into the other window at T+1
    // are safe) and vmcnt(0) confirms tile T's 16 gloads landed. Body: held
    // MFMA(ks3 of T-1) [reads aQ/bQ regs, before DS ks1 overwrites], issue
    // gloads(T+1) into NXT, then ds/MFMA ping-pong ks0..ks2; ks3 held.
#define TILE(CUR, NXT, FIRST, LAST)                                           \
    {                                                                         \
        asm volatile("s_waitcnt vmcnt(0) lgkmcnt(0)" ::: "memory");           \
        BAR;                                                                  \
        if (!(FIRST)) { MQ(aQ, bQ); }                                         \
        if (!(LAST)) {                                                        \
            _Pragma("unroll")                                                 \
            for (int i = 0; i < 16; ++i)                                      \
                GLOAD_LDS16(gSrc[i] + koff, (NXT) + dOff[i]);                 \
            koff += 64;                                                       \
        }                                                                     \
        DS_K(CUR, aP, bP, 0);                                                 \
        DS_K(CUR, aQ, bQ, 1);                                                 \
        MQ(aP, bP);                                                           \
        DS_K(CUR, aP, bP, 2);                                                 \
        MQ(aQ, bQ);                                                           \
        DS_K(CUR, aQ, bQ, 3);                                                 \
        MQ(aP, bP);                                                           \
    }

    // prologue: issue tile 0 into window b0
#pragma unroll
    for (int i = 0; i < 16; ++i) GLOAD_LDS16(gSrc[i], b0 + dOff[i]);

    int koff = 64;   // k element-offset of the next tile to issue (tile 1)

    TILE(b0, b1, 1, 0);                 // T0
#pragma unroll 1
    for (int t2 = 0; t2 < (NT - 2) / 2; ++t2) {   // T1..T62 (31 pairs)
        TILE(b1, b0, 0, 0);
        TILE(b0, b1, 0, 0);
    }
    TILE(b1, b0, 0, 1);                 // T63 (no prefetch)
    MQ(aQ, bQ);                         // drain held ks3 of T63

#undef TILE
#undef MQ
#undef DS_K

    // epilogue: bias add + store
    // 32x32 C/D layout: col = lane&31, row = (reg&3) + 8*(reg>>2) + 4*khalf
#pragma unroll
    for (int ni = 0; ni < 4; ++ni) {
        const int col = bn + wc2 * 128 + ni * 32 + l31;
        const float bv = bias[col];
#pragma unroll
        for (int mi = 0; mi < 4; ++mi) {
            const int rbase = bm + wr2 * 128 + mi * 32 + khalf * 4;
#pragma unroll
            for (int rg = 0; rg < 16; ++rg) {
                const int row = rbase + (rg & 3) + 8 * (rg >> 2);
                C[(size_t)row * Ndim + col] = acc[mi][ni][rg] + bv;
            }
        }
    }
}

// ---------------------------------------------------------------------------
// Fallback (only if ws too small): slow but correct fp32 row-per-block kernel
// ---------------------------------------------------------------------------
__global__ __launch_bounds__(256) void naive_row_kernel(
    const float* __restrict__ x, const float* __restrict__ W,
    const float* __restrict__ bias, const float* __restrict__ A,
    const float* __restrict__ Bm, float* __restrict__ out)
{
    __shared__ float sx[Kdim];
    __shared__ float st[ER];
    const int m = blockIdx.x;
    const float* xr = x + (size_t)m * Kdim;
    for (int i = threadIdx.x; i < Kdim; i += 256) sx[i] = xr[i];
    __syncthreads();
    if (threadIdx.x < ER) {
        const float* ar = A + (size_t)threadIdx.x * Kdim;
        float s = 0.f;
        for (int i = 0; i < Kdim; ++i) s += sx[i] * ar[i];
        st[threadIdx.x] = s;
    }
    __syncthreads();
    for (int o = threadIdx.x; o < Ndim; o += 256) {
        const float* wr = W + (size_t)o * Kdim;
        float s = bias[o];
        for (int i = 0; i < Kdim; ++i) s += sx[i] * wr[i];
        float l = 0.f;
        for (int e = 0; e < 8; ++e) {
            const float* bp = Bm + ((size_t)e * Ndim + o) * 8;
            for (int r = 0; r < 8; ++r) l += st[e * 8 + r] * bp[r];
        }
        out[(size_t)m * Ndim + o] = s + LSCALE * l;
    }
}

extern "C" void kernel_launch(void* const* d_in, const int* in_sizes, int n_in,
                              void* d_out, int out_size, void* d_ws, size_t ws_size,
                              hipStream_t stream)
{
    const float* x  = (const float*)d_in[0];
    const float* W  = (const float*)d_in[1];
    const float* b  = (const float*)d_in[2];
    const float* A  = (const float*)d_in[3];
    const float* Bm = (const float*)d_in[4];
    float* out = (float*)d_out;

    const size_t xb_bytes = (size_t)Mdim * Kdim * 2;   // 64 MB
    const size_t wb_bytes = (size_t)Ndim * Kdim * 2;   // 32 MB

    if (ws_size >= xb_bytes + wb_bytes) {
        u16* Xb = (u16*)d_ws;
        u16* Wb = (u16*)((char*)d_ws + xb_bytes);
        cvt_x_kernel<<<(Mdim * (size_t)Kdim) / 8 / 256, 256, 0, stream>>>(x, Xb);
        weff_kernel<<<dim3(Kdim / 128, Ndim / 64), 256, 0, stream>>>(W, A, Bm, Wb);
        gemm_bias_kernel<<<dim3((Mdim / BM) * (Ndim / BN)), 256, 0, stream>>>(Xb, Wb, b, out);
    } else {
        naive_row_kernel<<<Mdim, 256, 0, stream>>>(x, W, b, A, Bm, out);
    }
}

// Round 10
// 298.670 us; speedup vs baseline: 7.9756x; 1.0269x over previous
//
#include <hip/hip_runtime.h>
#include <hip/hip_bf16.h>

typedef unsigned short u16;
typedef __bf16 bf16x8 __attribute__((ext_vector_type(8)));
typedef float f32x4 __attribute__((ext_vector_type(4)));

// Problem constants (B=4, S=2048, D=4096, E=8, r=8)
constexpr int Mdim = 8192;   // B*S
constexpr int Ndim = 4096;   // D (output features)
constexpr int Kdim = 4096;   // D (input features)
constexpr int ER   = 64;     // E*r
constexpr float LSCALE = 2.0f;  // alpha/r = 16/8

// round-to-nearest-even fp32 -> bf16 (finite inputs)
__device__ __forceinline__ u16 f2bf(float f) {
    union { float f; unsigned u; } v; v.f = f;
    unsigned r = v.u + 0x7fffu + ((v.u >> 16) & 1u);
    return (u16)(r >> 16);
}

#define GLOAD_LDS16(g, l)                                             \
    __builtin_amdgcn_global_load_lds(                                 \
        (const __attribute__((address_space(1))) void*)(g),           \
        (__attribute__((address_space(3))) void*)(l), 16, 0, 0)

// ---------------------------------------------------------------------------
// Kernel 1: W_eff[o,i] = W[o,i] + SCALE * sum_{er} Bcat[o,er]*Acat[er,i] (bf16)
// ---------------------------------------------------------------------------
__global__ __launch_bounds__(256) void weff_kernel(
    const float* __restrict__ W, const float* __restrict__ A,
    const float* __restrict__ Bm, u16* __restrict__ Wb)
{
    __shared__ __align__(16) float sAc[ER][128];
    __shared__ __align__(16) float sBc[64][ER];

    const int t  = threadIdx.x;
    const int i0 = blockIdx.x * 128;
    const int o0 = blockIdx.y * 64;

#pragma unroll
    for (int p = 0; p < 8; ++p) {
        int lin = p * 1024 + t * 4;
        int er = lin >> 7, ci = lin & 127;
        *(float4*)&sAc[er][ci] = *(const float4*)(A + (size_t)er * Kdim + i0 + ci);
    }
    {
        int ol = t >> 2;
        int c  = (t & 3) * 16;
#pragma unroll
        for (int q = 0; q < 2; ++q) {
            int er = c + q * 8;
            int e  = er >> 3;
            const float* src = Bm + ((size_t)e * Ndim + (o0 + ol)) * 8;
            *(float4*)&sBc[ol][er]     = *(const float4*)(src);
            *(float4*)&sBc[ol][er + 4] = *(const float4*)(src + 4);
        }
    }
    __syncthreads();

    const int tx = t & 31;
    const int ty = t >> 5;
    float acc[8][4] = {};
#pragma unroll 4
    for (int er = 0; er < ER; ++er) {
        float4 a = *(const float4*)&sAc[er][tx * 4];
#pragma unroll
        for (int q = 0; q < 8; ++q) {
            float bv = sBc[q * 8 + ty][er];
            acc[q][0] += bv * a.x;
            acc[q][1] += bv * a.y;
            acc[q][2] += bv * a.z;
            acc[q][3] += bv * a.w;
        }
    }
#pragma unroll
    for (int q = 0; q < 8; ++q) {
        int o = o0 + q * 8 + ty;
        const float4 w = *(const float4*)(W + (size_t)o * Kdim + i0 + tx * 4);
        ushort4 st;
        st.x = f2bf(w.x + LSCALE * acc[q][0]);
        st.y = f2bf(w.y + LSCALE * acc[q][1]);
        st.z = f2bf(w.z + LSCALE * acc[q][2]);
        st.w = f2bf(w.w + LSCALE * acc[q][3]);
        *(ushort4*)(Wb + (size_t)o * Kdim + i0 + tx * 4) = st;
    }
}

// ---------------------------------------------------------------------------
// Kernel 2: x fp32 -> bf16, 8 elements/thread
// ---------------------------------------------------------------------------
__global__ __launch_bounds__(256) void cvt_x_kernel(
    const float* __restrict__ x, u16* __restrict__ xb)
{
    size_t i = (size_t)blockIdx.x * blockDim.x + threadIdx.x;
    const float4 v0 = *(const float4*)(x + i * 8);
    const float4 v1 = *(const float4*)(x + i * 8 + 4);
    uint4 o;
    o.x = (unsigned)f2bf(v0.x) | ((unsigned)f2bf(v0.y) << 16);
    o.y = (unsigned)f2bf(v0.z) | ((unsigned)f2bf(v0.w) << 16);
    o.z = (unsigned)f2bf(v1.x) | ((unsigned)f2bf(v1.y) << 16);
    o.w = (unsigned)f2bf(v1.z) | ((unsigned)f2bf(v1.w) << 16);
    *(uint4*)(xb + i * 8) = o;
}

// ---------------------------------------------------------------------------
// Kernel 3: 256x256x64 GEMM, FOUR waves of 128x128 output, 16x16x32 MFMA.
// Round-10 rationale: r9's 32x32 fragment reads span 32 rows -> 4-way bank
// conflict (1.678e7 measured). 16x16 fragments span 16 rows and match the
// r4-r6 swizzle that measured ZERO conflicts. Keep r9's halved LDS volume
// (4 waves x 32KB = 128KB reads/tile vs r6's 192KB) and its kk ping-pong,
// ordered so each DS batch issues BEFORE a 64-MFMA cluster that hides it:
//   top: vmcnt(0)+lgkmcnt(0); BAR; issue DS(kk0->P); issue 16 glds(T+1);
//        MQ(Q = kk1 of T-1, held); MQ(P); issue DS(kk1->Q), held to T+1.
// P/Q register sets are disjoint (no WAR); buffer lifetimes as in r6: the
// tile-top lgkmcnt(0) (pre-barrier) drains this wave's held-Q reads of the
// buffer that glds(T+1) will overwrite.
// acc[8][8] f32x4 = 256 (AGPR) + 128 frag VGPR; __launch_bounds__(256,1)
// gives the 512-reg budget (r9 measured 480 total, no spill).
// LDS 128 KiB: per buf {A[256][64], B[256][64]} bf16, double-buffered.
// Swizzle (both-sides involution, conflict-free for 16-row reads):
// stored chunk = global chunk ^ (row&7); staged via pre-swizzled source.
// ---------------------------------------------------------------------------
constexpr int BM = 256, BN = 256, BK = 64;
constexpr int NT = Kdim / BK;  // 64

__global__ __launch_bounds__(256, 1) void gemm_bias_kernel(
    const u16* __restrict__ Xb, const u16* __restrict__ Wb,
    const float* __restrict__ bias, float* __restrict__ C)
{
    __shared__ __align__(16) u16 lds[65536];   // 128 KiB

    const int t    = threadIdx.x;
    const int lane = t & 63;
    const int wv   = t >> 6;    // 0..3
    const int wr2  = wv >> 1;   // m-half: rows wr2*128..
    const int wc2  = wv & 1;    // n-half: cols wc2*128..

    // XCD-aware swizzle: 512 blocks = 8 XCDs x 64; each XCD owns a 16x4 region
    const int wg  = blockIdx.x;
    const int xcd = wg & 7, lid = wg >> 3;
    const int mt  = (xcd & 1) * 16 + (lid >> 2);   // 0..31
    const int ntl = (xcd >> 1) * 4 + (lid & 3);    // 0..15
    const int bm  = mt * BM;
    const int bn  = ntl * BN;

    u16* b0 = lds;            // buf: A at [0,16384), B at [16384,32768) u16
    u16* b1 = lds + 32768;

    // --- staging: 16 x global_load_lds(16B)/thread/K-tile, row-major
    // coalesced. Load j of A (j=0..7): chunk c = j*256+t, row = c>>3 =
    // j*32 + (t>>3), source col-chunk = (c ^ (c>>3)) & 7 = (t ^ (t>>3)) & 7
    // (j-invariant since j*32 = 0 mod 8 in both fields). Same for B.
    const int scl  = ((t ^ (t >> 3)) & 7) * 8;      // swizzled col (u16)
    const int rl   = t >> 3;                         // row low bits 0..31
    const u16* aBase = Xb + (size_t)(bm + rl) * Kdim + scl;
    const u16* bBase = Wb + (size_t)(bn + rl) * Kdim + scl;
    const int dA = t * 8;                            // LDS u16 offset (A)
    const int dB = 16384 + t * 8;                    // LDS u16 offset (B)
    constexpr int RSTEP = 32 * Kdim;                 // 32 rows in u16 elems

    // --- fragment ds_read addressing (swizzled, 16-row span) ---
    const int fr  = lane & 15;
    const int cp0 = ((((lane >> 4)    ) ^ (lane & 7)) & 7) * 8;   // kk=0
    const int cp1 = ((((lane >> 4) + 4) ^ (lane & 7)) & 7) * 8;   // kk=1

    f32x4 acc[8][8];
#pragma unroll
    for (int i = 0; i < 8; ++i)
#pragma unroll
        for (int j = 0; j < 8; ++j)
            acc[i][j] = f32x4{0.f, 0.f, 0.f, 0.f};

    bf16x8 aP[8], bP[8];   // kk0 fragment set
    bf16x8 aQ[8], bQ[8];   // kk1 fragment set (held across the tile boundary)

#define DS_K(BUF, AR, BR, CP)                                                 \
    _Pragma("unroll")                                                         \
    for (int mi = 0; mi < 8; ++mi)                                            \
        AR[mi] = *(const bf16x8*)                                             \
            &(BUF)[(wr2 * 128 + mi * 16 + fr) * 64 + (CP)];                   \
    _Pragma("unroll")                                                         \
    for (int ni = 0; ni < 8; ++ni)                                            \
        BR[ni] = *(const bf16x8*)                                             \
            &(BUF)[16384 + (wc2 * 128 + ni * 16 + fr) * 64 + (CP)];

#define MQ(AR, BR)                                                            \
    __builtin_amdgcn_s_setprio(1);                                            \
    _Pragma("unroll")                                                         \
    for (int mi = 0; mi < 8; ++mi)                                            \
        _Pragma("unroll")                                                     \
        for (int ni = 0; ni < 8; ++ni)                                        \
            acc[mi][ni] = __builtin_amdgcn_mfma_f32_16x16x32_bf16(            \
                AR[mi], BR[ni], acc[mi][ni], 0, 0, 0);                        \
    __builtin_amdgcn_s_setprio(0);

#define FENCE asm volatile("" ::: "memory")
#define BAR   __builtin_amdgcn_s_barrier(); FENCE

    // TILE(T): one barrier. vmcnt(0): tile T's 16 gloads landed (issued at
    // T-1; T+1's not yet issued). lgkmcnt(0): this wave's held-Q reads of
    // the other buffer are complete -> post-barrier gloads may overwrite it.
    // Body: issue DS(kk0->P) [hides under MQ(Q)]; issue gloads(T+1) [hide
    // under both MFMA clusters]; MQ(Q held from T-1); MQ(P) [compiler
    // inserts the counted lgkm wait]; issue DS(kk1->Q), held to T+1.
#define TILE(CUR, NXT, FIRST, LAST)                                           \
    {                                                                         \
        asm volatile("s_waitcnt vmcnt(0) lgkmcnt(0)" ::: "memory");           \
        BAR;                                                                  \
        DS_K(CUR, aP, bP, cp0);                                               \
        if (!(LAST)) {                                                        \
            _Pragma("unroll")                                                 \
            for (int j = 0; j < 8; ++j)                                       \
                GLOAD_LDS16(aBase + koff + j * RSTEP, (NXT) + dA + j * 2048); \
            _Pragma("unroll")                                                 \
            for (int j = 0; j < 8; ++j)                                       \
                GLOAD_LDS16(bBase + koff + j * RSTEP, (NXT) + dB + j * 2048); \
            koff += 64;                                                       \
        }                                                                     \
        if (!(FIRST)) { MQ(aQ, bQ); }                                         \
        MQ(aP, bP);                                                           \
        DS_K(CUR, aQ, bQ, cp1);                                               \
    }

    // prologue: issue tile 0 into buf0
#pragma unroll
    for (int j = 0; j < 8; ++j)
        GLOAD_LDS16(aBase + j * RSTEP, b0 + dA + j * 2048);
#pragma unroll
    for (int j = 0; j < 8; ++j)
        GLOAD_LDS16(bBase + j * RSTEP, b0 + dB + j * 2048);

    int koff = 64;   // k element-offset of the next tile to issue (tile 1)

    TILE(b0, b1, 1, 0);                 // T0
#pragma unroll 1
    for (int t2 = 0; t2 < (NT - 2) / 2; ++t2) {   // T1..T62 (31 pairs)
        TILE(b1, b0, 0, 0);
        TILE(b0, b1, 0, 0);
    }
    TILE(b1, b0, 0, 1);                 // T63 (no prefetch)
    MQ(aQ, bQ);                         // drain held kk1 of T63

#undef TILE
#undef MQ
#undef DS_K

    // epilogue: bias add + store (C/D layout: col=lane&15, row=(lane>>4)*4+j)
#pragma unroll
    for (int ni = 0; ni < 8; ++ni) {
        const int col = bn + wc2 * 128 + ni * 16 + (lane & 15);
        const float bv = bias[col];
#pragma unroll
        for (int mi = 0; mi < 8; ++mi) {
            const int rbase = bm + wr2 * 128 + mi * 16 + (lane >> 4) * 4;
#pragma unroll
            for (int j = 0; j < 4; ++j)
                C[(size_t)(rbase + j) * Ndim + col] = acc[mi][ni][j] + bv;
        }
    }
}

// ---------------------------------------------------------------------------
// Fallback (only if ws too small): slow but correct fp32 row-per-block kernel
// ---------------------------------------------------------------------------
__global__ __launch_bounds__(256) void naive_row_kernel(
    const float* __restrict__ x, const float* __restrict__ W,
    const float* __restrict__ bias, const float* __restrict__ A,
    const float* __restrict__ Bm, float* __restrict__ out)
{
    __shared__ float sx[Kdim];
    __shared__ float st[ER];
    const int m = blockIdx.x;
    const float* xr = x + (size_t)m * Kdim;
    for (int i = threadIdx.x; i < Kdim; i += 256) sx[i] = xr[i];
    __syncthreads();
    if (threadIdx.x < ER) {
        const float* ar = A + (size_t)threadIdx.x * Kdim;
        float s = 0.f;
        for (int i = 0; i < Kdim; ++i) s += sx[i] * ar[i];
        st[threadIdx.x] = s;
    }
    __syncthreads();
    for (int o = threadIdx.x; o < Ndim; o += 256) {
        const float* wr = W + (size_t)o * Kdim;
        float s = bias[o];
        for (int i = 0; i < Kdim; ++i) s += sx[i] * wr[i];
        float l = 0.f;
        for (int e = 0; e < 8; ++e) {
            const float* bp = Bm + ((size_t)e * Ndim + o) * 8;
            for (int r = 0; r < 8; ++r) l += st[e * 8 + r] * bp[r];
        }
        out[(size_t)m * Ndim + o] = s + LSCALE * l;
    }
}

extern "C" void kernel_launch(void* const* d_in, const int* in_sizes, int n_in,
                              void* d_out, int out_size, void* d_ws, size_t ws_size,
                              hipStream_t stream)
{
    const float* x  = (const float*)d_in[0];
    const float* W  = (const float*)d_in[1];
    const float* b  = (const float*)d_in[2];
    const float* A  = (const float*)d_in[3];
    const float* Bm = (const float*)d_in[4];
    float* out = (float*)d_out;

    const size_t xb_bytes = (size_t)Mdim * Kdim * 2;   // 64 MB
    const size_t wb_bytes = (size_t)Ndim * Kdim * 2;   // 32 MB

    if (ws_size >= xb_bytes + wb_bytes) {
        u16* Xb = (u16*)d_ws;
        u16* Wb = (u16*)((char*)d_ws + xb_bytes);
        cvt_x_kernel<<<(Mdim * (size_t)Kdim) / 8 / 256, 256, 0, stream>>>(x, Xb);
        weff_kernel<<<dim3(Kdim / 128, Ndim / 64), 256, 0, stream>>>(W, A, Bm, Wb);
        gemm_bias_kernel<<<dim3((Mdim / BM) * (Ndim / BN)), 256, 0, stream>>>(Xb, Wb, b, out);
    } else {
        naive_row_kernel<<<Mdim, 256, 0, stream>>>(x, W, b, A, Bm, out);
    }
}